// Round 1
// baseline (700.198 us; speedup 1.0000x reference)
//
#include <hip/hip_runtime.h>
#include <hip/hip_bf16.h>
#include <cfloat>

// Problem geometry (fixed by setup_inputs)
#define D       512
#define NCODES  1024
#define MROWS   32768          // 16 * 2048
#define BM      128
#define BN      128
#define BK      32
#define NT      (NCODES / BN)  // 8
#define KTILES  (D / BK)       // 16
#define THREADS 512
#define RSTRIDE 132            // padded LDS leading dim (dwords): (4k+m)%32 banking

// d_out layout (f32 elements): z_st, loss, dist, idx (idx stored as float)
#define ZST_OFF  0
#define LOSS_OFF 16777216
#define DIST_OFF 16777217
#define IDX_OFF  50331649

// ws layout (f32): z2[MROWS], e2[NCODES], loss_acc[1]
#define WS_E2    MROWS
#define WS_LOSS  (MROWS + NCODES)

// ---------------------------------------------------------------------------
// Kernel A: per-row squared norms for residual (z2) and emb (e2).
// One wave (64 lanes) per row; 512 f32 per row = 2 float4 per lane.
// Also zeroes the loss accumulator (stream-ordered before kernel B).
// ---------------------------------------------------------------------------
__global__ void rownorm_kernel(const float* __restrict__ residual,
                               const float* __restrict__ emb,
                               float* __restrict__ ws) {
    if (blockIdx.x == 0 && threadIdx.x == 0) ws[WS_LOSS] = 0.0f;
    const int gwave = (blockIdx.x * blockDim.x + threadIdx.x) >> 6;
    const int lane  = threadIdx.x & 63;
    if (gwave >= MROWS + NCODES) return;
    const float* src = (gwave < MROWS)
                     ? residual + (size_t)gwave * D
                     : emb + (size_t)(gwave - MROWS) * D;
    const float4* v = (const float4*)src;
    float4 a = v[lane];
    float4 b = v[lane + 64];
    float s = a.x*a.x + a.y*a.y + a.z*a.z + a.w*a.w
            + b.x*b.x + b.y*b.y + b.z*b.z + b.w*b.w;
#pragma unroll
    for (int off = 32; off > 0; off >>= 1) s += __shfl_xor(s, off);
    if (lane == 0) ws[gwave] = s;
}

// ---------------------------------------------------------------------------
// Kernel B: fused dist GEMM + dist store + argmin + z_st + loss partial.
// Grid: 256 blocks (one 128-row tile each). Block loops over all 8 N-tiles
// so the argmin is block-local. f32 vector FMA, 4x8 microtile per thread.
// ---------------------------------------------------------------------------
__launch_bounds__(THREADS)
__global__ void vq_main_kernel(const float* __restrict__ residual,
                               const float* __restrict__ emb,
                               float* __restrict__ ws,
                               float* __restrict__ out) {
    __shared__ float Rt[BK][RSTRIDE];   // k-major residual tile
    __shared__ float Et[BK][RSTRIDE];   // k-major emb tile
    __shared__ float sminv[BM][16];
    __shared__ int   smini[BM][16];
    __shared__ int   srowcode[BM];
    __shared__ float swsum[THREADS / 64];

    const float* z2 = ws;
    const float* e2 = ws + WS_E2;
    float* loss_acc = ws + WS_LOSS;

    const int t   = threadIdx.x;
    const int tn  = t & 15;    // 16 col-threads
    const int tm  = t >> 4;    // 32 row-threads
    const int row0 = blockIdx.x * BM;

    // staging decomposition: 1024 float4 per tile, 512 threads -> 2 each
    const int q  = t & 7;      // k-quad (k = q*4 .. q*4+3)
    const int r0 = t >> 3;     // 0..63 (row within tile)

    float z2v[4];
#pragma unroll
    for (int i = 0; i < 4; ++i) z2v[i] = z2[row0 + tm * 4 + i];

    float bminv[4];
    int   bmini[4];
#pragma unroll
    for (int i = 0; i < 4; ++i) { bminv[i] = FLT_MAX; bmini[i] = 0; }

    for (int nt = 0; nt < NT; ++nt) {
        const int n0 = nt * BN;
        float acc[4][8];
#pragma unroll
        for (int i = 0; i < 4; ++i)
#pragma unroll
            for (int j = 0; j < 8; ++j) acc[i][j] = 0.0f;

        for (int kt = 0; kt < KTILES; ++kt) {
            const int k0 = kt * BK;
#pragma unroll
            for (int it = 0; it < 2; ++it) {
                const int r = r0 + 64 * it;
                float4 rv = *(const float4*)&residual[(size_t)(row0 + r) * D + k0 + q * 4];
                float4 ev = *(const float4*)&emb[(size_t)(n0 + r) * D + k0 + q * 4];
                Rt[q * 4 + 0][r] = rv.x;
                Rt[q * 4 + 1][r] = rv.y;
                Rt[q * 4 + 2][r] = rv.z;
                Rt[q * 4 + 3][r] = rv.w;
                Et[q * 4 + 0][r] = ev.x;
                Et[q * 4 + 1][r] = ev.y;
                Et[q * 4 + 2][r] = ev.z;
                Et[q * 4 + 3][r] = ev.w;
            }
            __syncthreads();
#pragma unroll
            for (int kk = 0; kk < BK; ++kk) {
                float4 av  = *(const float4*)&Rt[kk][tm * 4];
                float4 bv0 = *(const float4*)&Et[kk][tn * 8];
                float4 bv1 = *(const float4*)&Et[kk][tn * 8 + 4];
                const float a4[4] = {av.x, av.y, av.z, av.w};
                const float b8[8] = {bv0.x, bv0.y, bv0.z, bv0.w,
                                     bv1.x, bv1.y, bv1.z, bv1.w};
#pragma unroll
                for (int i = 0; i < 4; ++i)
#pragma unroll
                    for (int j = 0; j < 8; ++j)
                        acc[i][j] = fmaf(a4[i], b8[j], acc[i][j]);
            }
            __syncthreads();
        }

        // epilogue for this N-tile: dist values + running argmin (no LDS use)
#pragma unroll
        for (int i = 0; i < 4; ++i) {
            const int row = row0 + tm * 4 + i;
            const size_t base = (size_t)DIST_OFF + (size_t)row * NCODES + n0 + tn * 8;
#pragma unroll
            for (int j = 0; j < 8; ++j) {
                const int col = n0 + tn * 8 + j;
                const float dv = (z2v[i] + e2[col]) - 2.0f * acc[i][j];
                out[base + j] = dv;   // dword stores (DIST_OFF is odd; no 16B align)
                if (dv < bminv[i]) { bminv[i] = dv; bmini[i] = col; }
            }
        }
    }

    // cross-thread argmin reduce (16 tn threads share each row)
#pragma unroll
    for (int i = 0; i < 4; ++i) {
        sminv[tm * 4 + i][tn] = bminv[i];
        smini[tm * 4 + i][tn] = bmini[i];
    }
    __syncthreads();
    if (t < BM) {
        float bv = sminv[t][0];
        int   bi = smini[t][0];
#pragma unroll
        for (int c = 1; c < 16; ++c) {
            const float v  = sminv[t][c];
            const int   ci = smini[t][c];
            if (v < bv || (v == bv && ci < bi)) { bv = v; bi = ci; }
        }
        srowcode[t] = bi;
        out[IDX_OFF + row0 + t] = (float)bi;   // harness reads d_out as f32
    }
    __syncthreads();

    // z_st + loss partial for the block's 128 rows
    float lsum = 0.0f;
    for (int e4 = t; e4 < BM * (D / 4); e4 += THREADS) {
        const int row = e4 >> 7;        // D/4 = 128 float4 per row
        const int dq  = e4 & 127;
        const size_t gi = (size_t)(row0 + row) * D + dq * 4;
        float4 rv = *(const float4*)&residual[gi];
        const int code = srowcode[row];
        float4 ev = *(const float4*)&emb[(size_t)code * D + dq * 4];
        float4 st;
        st.x = rv.x + (ev.x - rv.x);
        st.y = rv.y + (ev.y - rv.y);
        st.z = rv.z + (ev.z - rv.z);
        st.w = rv.w + (ev.w - rv.w);
        *(float4*)&out[ZST_OFF + gi] = st;
        const float dx = ev.x - rv.x, dy = ev.y - rv.y;
        const float dz = ev.z - rv.z, dw = ev.w - rv.w;
        lsum += dx * dx + dy * dy + dz * dz + dw * dw;
    }
#pragma unroll
    for (int off = 32; off > 0; off >>= 1) lsum += __shfl_xor(lsum, off);
    const int wave = t >> 6;
    const int lane = t & 63;
    if (lane == 0) swsum[wave] = lsum;
    __syncthreads();
    if (t == 0) {
        float s = 0.0f;
#pragma unroll
        for (int w = 0; w < THREADS / 64; ++w) s += swsum[w];
        atomicAdd(loss_acc, s);
    }
}

// ---------------------------------------------------------------------------
// Kernel C: finalize loss = (BETA + 1) * mean = 1.25 * sum / 16777216
// ---------------------------------------------------------------------------
__global__ void finalize_kernel(const float* __restrict__ ws,
                                float* __restrict__ out) {
    out[LOSS_OFF] = 1.25f * ws[WS_LOSS] / 16777216.0f;
}

extern "C" void kernel_launch(void* const* d_in, const int* in_sizes, int n_in,
                              void* d_out, int out_size, void* d_ws, size_t ws_size,
                              hipStream_t stream) {
    const float* residual = (const float*)d_in[0];
    const float* emb      = (const float*)d_in[1];
    float* out = (float*)d_out;
    float* ws  = (float*)d_ws;

    // 33792 rows, 4 waves/block of 256 threads
    rownorm_kernel<<<(MROWS + NCODES) / 4, 256, 0, stream>>>(residual, emb, ws);
    vq_main_kernel<<<MROWS / BM, THREADS, 0, stream>>>(residual, emb, ws, out);
    finalize_kernel<<<1, 1, 0, stream>>>(ws, out);
}

// Round 2
// 399.107 us; speedup vs baseline: 1.7544x; 1.7544x over previous
//
#include <hip/hip_runtime.h>
#include <cfloat>
#include <stdint.h>

// Problem geometry (fixed by setup_inputs)
#define D       512
#define NCODES  1024
#define MROWS   32768          // 16 * 2048

// d_out layout (f32 elements): z_st, loss, dist, idx (idx stored as float)
#define ZST_OFF  0
#define LOSS_OFF 16777216
#define DIST_OFF 16777217ull
#define IDX_OFF  50331649

// ws layout: bytes [0, 2 MB) = split-E tile images; then f32 z2/e2/loss
#define WS_Z2   524288
#define WS_E2   557056
#define WS_LOSS 558080

typedef __attribute__((ext_vector_type(4))) float f32x4;
typedef __attribute__((ext_vector_type(4))) int   i32x4;
typedef __bf16 bf16v8 __attribute__((ext_vector_type(8)));

static __device__ __forceinline__ uint32_t f2bf(float x) {
    // round-to-nearest-even bf16, returned as low 16 bits
    uint32_t u = __float_as_uint(x);
    return (u + 0x7fffu + ((u >> 16) & 1u)) >> 16;
}
static __device__ __forceinline__ float bf2f(uint32_t h) {
    return __uint_as_float(h << 16);
}
static __device__ __forceinline__ f32x4 MFMA(bf16v8 a, bf16v8 b, f32x4 c) {
    return __builtin_amdgcn_mfma_f32_16x16x32_bf16(a, b, c, 0, 0, 0);
}

// ---------------------------------------------------------------------------
// Pre-pass: one wave per row (residual rows then emb rows).
//  - computes row squared norm (z2 / e2)
//  - splits f32 -> bf16 hi + bf16 lo and writes them into swizzled,
//    global_load_lds-ready tile images:
//      residual -> z_st region of d_out  [bm(256)][kt(8)][comp(2)][128r][64k]
//      emb      -> ws                    [nt(4)][kt(8)][comp(2)][256c][64k]
//    within a tile: byte = r*128 + ((k2b) ^ ((r&7)<<4))   (16B-block XOR swizzle)
//  - zeroes the loss accumulator
// Lane <-> k-chunk: lane handles 8 consecutive k (= one 16B bf16 chunk/comp).
// ---------------------------------------------------------------------------
__global__ void prepass_kernel(const float* __restrict__ residual,
                               const float* __restrict__ emb,
                               float* __restrict__ ws,
                               float* __restrict__ out) {
    if (blockIdx.x == 0 && threadIdx.x == 0) ws[WS_LOSS] = 0.0f;
    const int gwave = (int)((blockIdx.x * blockDim.x + threadIdx.x) >> 6);
    const int lane  = threadIdx.x & 63;
    const bool isA  = gwave < MROWS;
    const float* src = isA ? residual + (size_t)gwave * D
                           : emb + (size_t)(gwave - MROWS) * D;
    const float4* vp = (const float4*)src;
    float4 x0 = vp[lane * 2];
    float4 x1 = vp[lane * 2 + 1];
    float xs[8] = {x0.x, x0.y, x0.z, x0.w, x1.x, x1.y, x1.z, x1.w};
    uint32_t hp[4], lp[4];
    float s = 0.f;
#pragma unroll
    for (int i = 0; i < 4; ++i) {
        float a = xs[2 * i], b = xs[2 * i + 1];
        s += a * a + b * b;
        uint32_t h0 = f2bf(a), h1 = f2bf(b);
        uint32_t l0 = f2bf(a - bf2f(h0)), l1 = f2bf(b - bf2f(h1));
        hp[i] = h0 | (h1 << 16);
        lp[i] = l0 | (l1 << 16);
    }
#pragma unroll
    for (int off = 32; off > 0; off >>= 1) s += __shfl_xor(s, off);

    const int kt = lane >> 3, c8 = lane & 7;
    i32x4 hv = {(int)hp[0], (int)hp[1], (int)hp[2], (int)hp[3]};
    i32x4 lv = {(int)lp[0], (int)lp[1], (int)lp[2], (int)lp[3]};
    if (isA) {
        const int bm = gwave >> 7, rl = gwave & 127;
        char* dst = (char*)out + (size_t)bm * 262144 + (size_t)kt * 32768
                  + rl * 128 + ((c8 * 16) ^ ((rl & 7) << 4));
        *(i32x4*)dst = hv;
        *(i32x4*)(dst + 16384) = lv;     // comp stride (A): 128*64*2B
        if (lane == 0) ws[WS_Z2 + gwave] = s;
    } else {
        const int n = gwave - MROWS, nt = n >> 8, cl = n & 255;
        char* dst = (char*)ws + (size_t)nt * 524288 + (size_t)kt * 65536
                  + cl * 128 + ((c8 * 16) ^ ((cl & 7) << 4));
        *(i32x4*)dst = hv;
        *(i32x4*)(dst + 32768) = lv;     // comp stride (B): 256*64*2B
        if (lane == 0) ws[WS_E2 + n] = s;
    }
}

// ---------------------------------------------------------------------------
// Main kernel: 256 blocks x 512 threads (8 waves, 2(M) x 4(N) wave grid).
// Block tile: 128 rows x 256 cols per nt (NT=4 sweeps cover N=1024).
// Wave tile: 64 x 64 -> 4 m-frags x 4 n-frags, mfma_f32_16x16x32_bf16,
// 3 products (hh, hl, lh) accumulate into the same f32 acc.
// LDS (96 KB): [A_hi 16K][A_lo 16K][B_hi 32K][B_lo 32K], staged per kt via
// global_load_lds_dwordx4 from the pre-swizzled images; frag ds_read_b128
// uses the same XOR swizzle -> <=2-way banking (free).
// ---------------------------------------------------------------------------
__launch_bounds__(512, 2)
__global__ void vq_main_kernel(const float* __restrict__ residual,
                               const float* __restrict__ emb,
                               float* __restrict__ ws,
                               float* __restrict__ out) {
    __shared__ __align__(16) char smem[98304];
    const int tid  = threadIdx.x;
    const int wid  = tid >> 6, lane = tid & 63;
    const int ln15 = lane & 15, kg = lane >> 4;
    const int wm   = wid >> 2, wn = wid & 3;
    const int bm   = blockIdx.x;
    const int row0 = bm * 128;

    // per-thread rows: local r = wm*64 + mf*16 + kg*4 + j
    float z2r[16];
#pragma unroll
    for (int mf = 0; mf < 4; ++mf)
#pragma unroll
        for (int j = 0; j < 4; ++j)
            z2r[mf * 4 + j] = ws[WS_Z2 + row0 + wm * 64 + mf * 16 + kg * 4 + j];

    float runv[16];
    int   runi[16];
#pragma unroll
    for (int li = 0; li < 16; ++li) { runv[li] = FLT_MAX; runi[li] = 0; }

    // LDS frag byte offsets (swizzled)
    int aoff[4][2], boff[4][2];
#pragma unroll
    for (int mf = 0; mf < 4; ++mf) {
        const int rA = wm * 64 + mf * 16 + ln15;
#pragma unroll
        for (int ks = 0; ks < 2; ++ks)
            aoff[mf][ks] = rA * 128 + ((ks * 64 + kg * 16) ^ ((rA & 7) << 4));
    }
#pragma unroll
    for (int nf = 0; nf < 4; ++nf) {
        const int cB = wn * 64 + nf * 16 + ln15;
#pragma unroll
        for (int ks = 0; ks < 2; ++ks)
            boff[nf][ks] = 32768 + cB * 128 + ((ks * 64 + kg * 16) ^ ((cB & 7) << 4));
    }

    const char* srcA = (const char*)out + (size_t)bm * 262144;  // split-R scratch
    const char* srcB = (const char*)ws;                         // split-E images

    for (int nt = 0; nt < 4; ++nt) {
        f32x4 acc[4][4];
#pragma unroll
        for (int mf = 0; mf < 4; ++mf)
#pragma unroll
            for (int nf = 0; nf < 4; ++nf) acc[mf][nf] = 0.f;

        for (int kt = 0; kt < 8; ++kt) {
            __syncthreads();   // previous phase done reading LDS
            {
                const char* ga = srcA + (size_t)kt * 32768 + wid * 1024 + lane * 16;
                char* la = smem + wid * 1024;
#pragma unroll
                for (int i = 0; i < 4; ++i)
                    __builtin_amdgcn_global_load_lds((const uint32_t*)(ga + i * 8192),
                                                     (uint32_t*)(la + i * 8192), 16, 0, 0);
                const char* gb = srcB + (size_t)nt * 524288 + (size_t)kt * 65536
                               + wid * 1024 + lane * 16;
                char* lb = smem + 32768 + wid * 1024;
#pragma unroll
                for (int i = 0; i < 8; ++i)
                    __builtin_amdgcn_global_load_lds((const uint32_t*)(gb + i * 8192),
                                                     (uint32_t*)(lb + i * 8192), 16, 0, 0);
            }
            __syncthreads();   // loads complete (compiler drains vmcnt)

#pragma unroll
            for (int ks = 0; ks < 2; ++ks) {
                bf16v8 ah[4], al[4], bh[4], bl[4];
#pragma unroll
                for (int mf = 0; mf < 4; ++mf) {
                    ah[mf] = *(const bf16v8*)(smem + aoff[mf][ks]);
                    al[mf] = *(const bf16v8*)(smem + aoff[mf][ks] + 16384);
                }
#pragma unroll
                for (int nf = 0; nf < 4; ++nf) {
                    bh[nf] = *(const bf16v8*)(smem + boff[nf][ks]);
                    bl[nf] = *(const bf16v8*)(smem + boff[nf][ks] + 32768);
                }
#pragma unroll
                for (int mf = 0; mf < 4; ++mf)
#pragma unroll
                    for (int nf = 0; nf < 4; ++nf) {
                        acc[mf][nf] = MFMA(ah[mf], bh[nf], acc[mf][nf]);
                        acc[mf][nf] = MFMA(ah[mf], bl[nf], acc[mf][nf]);
                        acc[mf][nf] = MFMA(al[mf], bh[nf], acc[mf][nf]);
                    }
            }
        }

        // epilogue for this nt: dist store + running argmin
        float e2v[4];
#pragma unroll
        for (int nf = 0; nf < 4; ++nf)
            e2v[nf] = ws[WS_E2 + nt * 256 + wn * 64 + nf * 16 + ln15];
#pragma unroll
        for (int mf = 0; mf < 4; ++mf)
#pragma unroll
            for (int nf = 0; nf < 4; ++nf)
#pragma unroll
                for (int j = 0; j < 4; ++j) {
                    const float dv = (z2r[mf * 4 + j] + e2v[nf]) - 2.0f * acc[mf][nf][j];
                    const int grow = row0 + wm * 64 + mf * 16 + kg * 4 + j;
                    const int gcol = nt * 256 + wn * 64 + nf * 16 + ln15;
                    out[DIST_OFF + (size_t)grow * 1024 + gcol] = dv;
                    const int li = mf * 4 + j;
                    if (dv < runv[li]) { runv[li] = dv; runi[li] = gcol; }
                }
    }

    // argmin reduce across the 16 lanes sharing each row (vary ln15)
#pragma unroll
    for (int off = 1; off < 16; off <<= 1) {
#pragma unroll
        for (int li = 0; li < 16; ++li) {
            const float ov = __shfl_xor(runv[li], off);
            const int   oi = __shfl_xor(runi[li], off);
            if (ov < runv[li] || (ov == runv[li] && oi < runi[li])) {
                runv[li] = ov; runi[li] = oi;
            }
        }
    }

    // cross-wave (wn) combine via LDS; smem is free after last barrier below
    float* smin = (float*)smem;            // [128][4]
    int*   sidx = (int*)(smem + 2048);     // [128][4]
    int*   srowcode = (int*)(smem + 4096); // [128]
    float* swsum = (float*)(smem + 4608);  // [8]
    __syncthreads();   // all waves done with frag reads
    if (ln15 == 0) {
#pragma unroll
        for (int mf = 0; mf < 4; ++mf)
#pragma unroll
            for (int j = 0; j < 4; ++j) {
                const int rl = wm * 64 + mf * 16 + kg * 4 + j;
                smin[rl * 4 + wn] = runv[mf * 4 + j];
                sidx[rl * 4 + wn] = runi[mf * 4 + j];
            }
    }
    __syncthreads();
    if (tid < 128) {
        float bv = smin[tid * 4];
        int   bi = sidx[tid * 4];
#pragma unroll
        for (int c = 1; c < 4; ++c) {
            const float v  = smin[tid * 4 + c];
            const int   ci = sidx[tid * 4 + c];
            if (v < bv || (v == bv && ci < bi)) { bv = v; bi = ci; }
        }
        srowcode[tid] = bi;
        out[IDX_OFF + row0 + tid] = (float)bi;
    }
    __syncthreads();

    // z_st + loss partial (overwrites the split-R scratch with final z_st)
    float lsum = 0.0f;
    for (int e4 = tid; e4 < 128 * 128; e4 += 512) {
        const int rl = e4 >> 7, dq = e4 & 127;
        const size_t gi = (size_t)(row0 + rl) * D + dq * 4;
        float4 rv = *(const float4*)&residual[gi];
        const int code = srowcode[rl];
        float4 ev = *(const float4*)&emb[(size_t)code * D + dq * 4];
        float4 st;
        const float dx = ev.x - rv.x, dy = ev.y - rv.y;
        const float dz = ev.z - rv.z, dw = ev.w - rv.w;
        st.x = rv.x + dx; st.y = rv.y + dy; st.z = rv.z + dz; st.w = rv.w + dw;
        *(float4*)&out[ZST_OFF + gi] = st;
        lsum += dx * dx + dy * dy + dz * dz + dw * dw;
    }
#pragma unroll
    for (int off = 32; off > 0; off >>= 1) lsum += __shfl_xor(lsum, off);
    if (lane == 0) swsum[wid] = lsum;
    __syncthreads();
    if (tid == 0) {
        float s = 0.0f;
#pragma unroll
        for (int w = 0; w < 8; ++w) s += swsum[w];
        atomicAdd(&ws[WS_LOSS], s);
    }
}

// ---------------------------------------------------------------------------
// Finalize: loss = (BETA + 1) * mean = 1.25 * sum / 16777216
// ---------------------------------------------------------------------------
__global__ void finalize_kernel(const float* __restrict__ ws,
                                float* __restrict__ out) {
    out[LOSS_OFF] = 1.25f * ws[WS_LOSS] / 16777216.0f;
}

extern "C" void kernel_launch(void* const* d_in, const int* in_sizes, int n_in,
                              void* d_out, int out_size, void* d_ws, size_t ws_size,
                              hipStream_t stream) {
    const float* residual = (const float*)d_in[0];
    const float* emb      = (const float*)d_in[1];
    float* out = (float*)d_out;
    float* ws  = (float*)d_ws;

    // 33792 rows, one wave each -> 8448 blocks of 256 threads (exact)
    prepass_kernel<<<8448, 256, 0, stream>>>(residual, emb, ws, out);
    vq_main_kernel<<<MROWS / 128, 512, 0, stream>>>(residual, emb, ws, out);
    finalize_kernel<<<1, 1, 0, stream>>>(ws, out);
}